// Round 1
// 251.898 us; speedup vs baseline: 1.0091x; 1.0091x over previous
//
#include <hip/hip_runtime.h>
#include <math.h>

#define HH 128
#define WW 128

// One block per batch element. 4 waves/block; each wave owns a contiguous
// 16 KiB span of the image (32 rows). Per lane: x is FIXED across all 16
// iterations (4 consecutive pixels), y advances by 2 per iteration.
// out[b,y,x] = exp2( P'*dx^2 + Q'*dx*dy + R'*dy^2 + log2(norm) )
// with P',Q',R' pre-scaled by log2(e); per-pixel cost = FMA + ADD + v_exp_f32.
__global__ __launch_bounds__(256) void MomentsToImage_kernel(
    const float* __restrict__ moments, float* __restrict__ out) {
    const int b = blockIdx.x;
    const float* m = moments + (size_t)b * 6;

    const float sx = (float)(WW - 1);   // 127
    const float sy = (float)(HH - 1);   // 127

    float m0 = m[0], m1 = m[1], m2 = m[2], m3 = m[3], m4 = m[4], m5 = m[5];

    // --- preamble: identical math to the passing kernel ---
    float mux = tanhf(m0) * (sx * 0.5f) + (sx * 0.5f);
    float muy = tanhf(m1) * (sy * 0.5f) + (sy * 0.5f);

    float t0 = fminf(fmaxf(tanhf(m2), 0.03f),   1.0f);
    float t1 = fminf(fmaxf(tanhf(m3), -0.999f), 0.999f);
    float t2 = fminf(fmaxf(tanhf(m4), 0.03f),   1.0f);

    float a  = t0 * (3.0f * sx);
    float bb = t1 * sqrtf(t0 * t2 * (9.0f * sx * sy));
    float c  = t2 * (3.0f * sy);

    float det = a * c - bb * bb;
    float it  = 10.0f / (1.0f + __expf(-m5));          // 10 * sigmoid(m5)
    float norm = it / (6.28318530717958647692f * sqrtf(det));

    float inv_det = 1.0f / det;
    const float L2E = 1.4426950408889634f;             // log2(e)
    float P = (-0.5f * c * inv_det) * L2E;   // coeff of dx^2   (exp2 domain)
    float Q = ( bb * inv_det)       * L2E;   // coeff of dx*dy
    float R = (-0.5f * a * inv_det) * L2E;   // coeff of dy^2
    float n2 = __builtin_amdgcn_logf(norm);  // log2(norm), norm > 0 always

    const int lane = threadIdx.x & 63;
    const int wid  = threadIdx.x >> 6;       // wave id 0..3

    // x for this lane: 4*(lane&31), constant across iterations.
    float d0 = (float)((lane & 31) << 2) - mux;
    float d1 = d0 + 1.0f;
    float d2 = d0 + 2.0f;
    float d3 = d0 + 3.0f;

    // Hoisted per-pixel-column constants (norm folded into A_k).
    float A0 = P * d0 * d0 + n2, B0 = Q * d0;
    float A1 = P * d1 * d1 + n2, B1 = Q * d1;
    float A2 = P * d2 * d2 + n2, B2 = Q * d2;
    float A3 = P * d3 * d3 + n2, B3 = Q * d3;

    // y for this lane at iteration 0: wid*32 + (lane>>5); +2 per iteration.
    float dy = (float)((wid << 5) + (lane >> 5)) - muy;

    // Wave-linear float4 stream: wave `wid` writes [wid*16KiB, +16KiB).
    float4* out4 = (float4*)(out + (size_t)b * (HH * WW)) + (wid << 10) + lane;

    #pragma unroll
    for (int i = 0; i < 16; ++i) {
        float dy2 = dy * dy;
        float rb  = R * dy2;
        float4 o;
        o.x = __builtin_amdgcn_exp2f(fmaf(B0, dy, A0) + rb);
        o.y = __builtin_amdgcn_exp2f(fmaf(B1, dy, A1) + rb);
        o.z = __builtin_amdgcn_exp2f(fmaf(B2, dy, A2) + rb);
        o.w = __builtin_amdgcn_exp2f(fmaf(B3, dy, A3) + rb);
        out4[i * 64] = o;
        dy += 2.0f;
    }
}

extern "C" void kernel_launch(void* const* d_in, const int* in_sizes, int n_in,
                              void* d_out, int out_size, void* d_ws, size_t ws_size,
                              hipStream_t stream) {
    const float* moments = (const float*)d_in[0];
    float* out = (float*)d_out;
    int B = in_sizes[0] / 6;             // 4096
    MomentsToImage_kernel<<<dim3(B), dim3(256), 0, stream>>>(moments, out);
}